// Round 5
// baseline (476.232 us; speedup 1.0000x reference)
//
#include <hip/hip_runtime.h>

#define NN 64
#define CC 128
#define TT 2048
#define SS 9
#define PAD 4
#define EPSF 1e-5f
#define TL 64                  // t columns per tile
#define ROWS (CC + 2 * PAD)    // 136 staged rows
#define LSTRIDE (TL + 1)       // 65: odd -> conflict-free lane=c reads
#define NB 16                  // stat buckets
#define GRID 1024              // 4 blocks/CU x 256 CU -> all co-resident

// Single-pass persistent kernel:
//  A) 2 tiles/block: stage shifted x -> LDS, conv -> res[][] in VGPRs, stats in regs
//  B) bucketed atomics -> hand-rolled grid barrier (all 1024 blocks resident)
//  C) per-thread fold of buckets -> g,b ; normalize res -> LDS transpose -> store
__global__ __launch_bounds__(256, 4) void s2conv_onepass(
    const float* __restrict__ x, const float* __restrict__ cw,
    const float* __restrict__ gamma, const float* __restrict__ beta,
    float* __restrict__ ws, float* __restrict__ out)
{
    __shared__ float ls[ROWS * LSTRIDE];   // 35.4 KB

    float* buckets = ws;                             // [NB][2][CC]
    unsigned* bar  = (unsigned*)(ws + NB * 2 * CC);  // barrier counter

    const int tid  = threadIdx.x;
    const int w    = tid >> 6;        // wave 0..3
    const int lane = tid & 63;
    const int bid  = blockIdx.x;
    const int n    = bid >> 4;        // 64 batches
    const int tcb  = bid & 15;        // tile-column base; tiles tcb and tcb+16
    const int c    = tid & (CC - 1);  // this thread's output channel
    const int jb   = (tid >> 7) * (TL / 2);   // 0 or 32

    const float* __restrict__ xn = x + (size_t)n * CC * TT;

    float wv[SS];
#pragma unroll
    for (int s = 0; s < SS; ++s) wv[s] = cw[c * SS + s];

    float res[2][TL / 2];             // 64 VGPRs of conv results
    float s1 = 0.f, s2 = 0.f;

    // ---------------- phase A: conv both tiles ----------------
#pragma unroll
    for (int k = 0; k < 2; ++k) {
        const int t0 = (tcb + 16 * k) * TL;
        if (k) __syncthreads();       // prior tile's conv reads complete
#pragma unroll
        for (int i = 0; i < ROWS / 4; ++i) {     // 34 rows per wave
            const int r  = w * 34 + i;
            const int c2 = r - PAD;
            float v = 0.f;
            if (c2 >= 0 && c2 < CC) {            // wave-uniform
                const int sh = (c2 % SS) - PAD;
                const int t  = t0 + lane - sh;
                if (t >= 0 && t < TT) v = xn[c2 * TT + t];
            }
            ls[r * LSTRIDE + lane] = v;
        }
        __syncthreads();
        const int base = c * LSTRIDE + jb;
#pragma unroll
        for (int j = 0; j < TL / 2; ++j) {
            float acc = 0.f;
#pragma unroll
            for (int s = 0; s < SS; ++s)
                acc = fmaf(wv[s], ls[base + s * LSTRIDE + j], acc);
            res[k][j] = acc;
            s1 += acc;
            s2 = fmaf(acc, acc, s2);
        }
    }

    // ---------------- phase B: stats + grid barrier ----------------
    {
        float* bs = buckets + (bid & (NB - 1)) * 2 * CC;
        atomicAdd(&bs[c], s1);                   // ~128 serialized adds/addr
        atomicAdd(&bs[CC + c], s2);
    }
    __syncthreads();                  // drains this block's atomics (vmcnt)
    if (tid == 0) {
        __threadfence();              // release
        atomicAdd(bar, 1u);
        while (atomicAdd(bar, 0u) < (unsigned)GRID)
            __builtin_amdgcn_s_sleep(8);         // backoff: cut RMW contention
    }
    __syncthreads();
    __threadfence();                  // acquire: invalidate stale L1/L2 lines

    // ---------------- phase C: fold stats, normalize, store ----------------
    float g, b;
    {
        float t1 = 0.f, t2 = 0.f;
#pragma unroll
        for (int kk = 0; kk < NB; ++kk) {        // L2-hot, coalesced per wave
            t1 += buckets[kk * 2 * CC + c];
            t2 += buckets[kk * 2 * CC + CC + c];
        }
        const float inv_cnt = 1.0f / (float)(NN * TT);
        const float mean = t1 * inv_cnt;
        const float var  = t2 * inv_cnt - mean * mean;
        const float inv  = rsqrtf(var + EPSF);
        g = gamma[c] * inv;
        b = beta[c] - mean * g;
    }

#pragma unroll
    for (int k = 0; k < 2; ++k) {
        const int t0 = (tcb + 16 * k) * TL;
        __syncthreads();              // ls free for reuse
#pragma unroll
        for (int j = 0; j < TL / 2; ++j) {
            const float v = fmaf(res[k][j], g, b);
            ls[c * LSTRIDE + jb + j] = v > 0.f ? v : 0.f;
        }
        __syncthreads();
        float* __restrict__ on = out + (size_t)n * CC * TT + t0;
#pragma unroll
        for (int i = 0; i < 32; ++i) {           // 32 rows per wave, 256B/instr
            const int r = w * 32 + i;
            on[(size_t)r * TT + lane] = ls[r * LSTRIDE + lane];
        }
    }
}

extern "C" void kernel_launch(void* const* d_in, const int* in_sizes, int n_in,
                              void* d_out, int out_size, void* d_ws, size_t ws_size,
                              hipStream_t stream)
{
    const float* x     = (const float*)d_in[0];
    const float* cw    = (const float*)d_in[1];
    const float* gamma = (const float*)d_in[2];
    const float* beta  = (const float*)d_in[3];
    float* out = (float*)d_out;
    float* ws  = (float*)d_ws;

    // zero buckets + barrier word (d_ws is re-poisoned before every launch)
    hipMemsetAsync(d_ws, 0, (NB * 2 * CC + 4) * sizeof(float), stream);
    s2conv_onepass<<<GRID, 256, 0, stream>>>(x, cw, gamma, beta, ws, out);
}

// Round 6
// 155.271 us; speedup vs baseline: 3.0671x; 3.0671x over previous
//
#include <hip/hip_runtime.h>

#define NN 64
#define CC 128
#define TT 2048
#define SS 9
#define PAD 4
#define EPSF 1e-5f
#define TL 32                 // t columns per block
#define ROWS (CC + 2 * PAD)   // 136 staged rows
#define STRIDE (TL + 1)       // 33: odd -> conflict-free c-per-lane reads
#define NB 16                 // stat buckets

// K1: stage shifted tile -> conv -> raw conv to out (LDS transpose, coalesced)
//     + per-thread sum/sumsq -> pair-combined -> bucketed global atomics.
__global__ __launch_bounds__(256, 8) void conv_store_stats(
    const float* __restrict__ x, const float* __restrict__ cw,
    float* __restrict__ buckets, float* __restrict__ out)
{
    __shared__ float ls[ROWS * STRIDE];   // 17952 B
    __shared__ float sred[512];           // +2048 B -> 20000 B, 8 blocks/CU

    const int n     = blockIdx.y;
    const int t0    = blockIdx.x * TL;
    const int tid   = threadIdx.x;
    const int lane  = tid & 63;
    const int wid   = tid >> 6;
    const int col   = lane & 31;
    const int rhalf = lane >> 5;          // two 32-lane rows per wave instr
    const float* __restrict__ xn = x + (size_t)n * CC * TT;

    // ---- stage: ls[c2+4][j] = xs[n, c2, t0+j] (pre-shifted, zero-padded) ----
#pragma unroll
    for (int i = 0; i < 17; ++i) {        // 34 rows per wave, 2 per iter
        const int r  = wid * 34 + 2 * i + rhalf;
        const int c2 = r - PAD;
        float v = 0.f;
        if (c2 >= 0 && c2 < CC) {
            const int sh = (c2 % SS) - PAD;
            const int t  = t0 + col - sh;
            if (t >= 0 && t < TT) v = xn[c2 * TT + t];
        }
        ls[r * STRIDE + col] = v;
    }

    const int c  = tid & (CC - 1);        // fixed output channel per thread
    const int jb = (tid >> 7) * (TL / 2); // 0 or 16
    float wv[SS];
#pragma unroll
    for (int s = 0; s < SS; ++s) wv[s] = cw[c * SS + s];

    __syncthreads();

    // ---- conv: rows c..c+8, conflict-free (STRIDE odd, c = lane) ----
    const int base = c * STRIDE + jb;
    float res[TL / 2];
    float s1 = 0.f, s2 = 0.f;
#pragma unroll
    for (int j = 0; j < TL / 2; ++j) {
        float acc = 0.f;
#pragma unroll
        for (int s = 0; s < SS; ++s)
            acc = fmaf(wv[s], ls[base + s * STRIDE + j], acc);
        res[j] = acc;
        s1 += acc;
        s2 = fmaf(acc, acc, s2);
    }

    // ---- transpose res into ls + stage stats partials ----
    __syncthreads();                      // conv reads done; safe to overwrite
#pragma unroll
    for (int j = 0; j < TL / 2; ++j)
        ls[c * STRIDE + jb + j] = res[j];
    sred[tid]       = s1;
    sred[256 + tid] = s2;
    __syncthreads();

    // ---- bucketed atomics: pair (tid, tid+128) combined -> 1 add per (blk,c) ----
    if (tid < CC) {
        float* bs = buckets + ((blockIdx.x + blockIdx.y) & (NB - 1)) * 2 * CC;
        atomicAdd(&bs[tid],      sred[tid]       + sred[tid + 128]);
        atomicAdd(&bs[CC + tid], sred[256 + tid] + sred[256 + tid + 128]);
    }

    // ---- raw conv -> out, coalesced ----
    float* __restrict__ on = out + (size_t)n * CC * TT + t0;
#pragma unroll
    for (int i = 0; i < 16; ++i) {        // 32 rows per wave, 2 per iter
        const int r = wid * 32 + 2 * i + rhalf;
        on[(size_t)r * TT + col] = ls[r * STRIDE + col];
    }
}

// K2: fused stats-fold (block-uniform scalar loads) + normalize + ReLU.
// One block per (n,c) row; in-place float4 RMW on out.
__global__ __launch_bounds__(256, 8) void norm_relu(
    const float* __restrict__ buckets, const float* __restrict__ gamma,
    const float* __restrict__ beta, float* __restrict__ out)
{
    const int row = blockIdx.x;           // 8192 = NN*CC rows
    const int c   = row & (CC - 1);       // block-uniform

    float t1 = 0.f, t2 = 0.f;
#pragma unroll
    for (int k = 0; k < NB; ++k) {        // uniform addresses -> scalar loads
        t1 += buckets[k * 2 * CC + c];
        t2 += buckets[k * 2 * CC + CC + c];
    }
    const float inv_cnt = 1.0f / (float)(NN * TT);
    const float mean = t1 * inv_cnt;
    const float var  = t2 * inv_cnt - mean * mean;
    const float inv  = rsqrtf(var + EPSF);
    const float g = gamma[c] * inv;
    const float b = beta[c] - mean * g;

    float4* __restrict__ o4 = (float4*)(out + (size_t)row * TT);
#pragma unroll
    for (int k = 0; k < 2; ++k) {         // 512 float4 per row / 256 threads
        const int i = threadIdx.x + k * 256;
        float4 v = o4[i];
        v.x = fmaf(v.x, g, b); v.y = fmaf(v.y, g, b);
        v.z = fmaf(v.z, g, b); v.w = fmaf(v.w, g, b);
        v.x = v.x > 0.f ? v.x : 0.f;
        v.y = v.y > 0.f ? v.y : 0.f;
        v.z = v.z > 0.f ? v.z : 0.f;
        v.w = v.w > 0.f ? v.w : 0.f;
        o4[i] = v;
    }
}

extern "C" void kernel_launch(void* const* d_in, const int* in_sizes, int n_in,
                              void* d_out, int out_size, void* d_ws, size_t ws_size,
                              hipStream_t stream)
{
    const float* x     = (const float*)d_in[0];
    const float* cw    = (const float*)d_in[1];
    const float* gamma = (const float*)d_in[2];
    const float* beta  = (const float*)d_in[3];
    float* out     = (float*)d_out;
    float* buckets = (float*)d_ws;        // [NB][2][CC]

    hipMemsetAsync(buckets, 0, (size_t)NB * 2 * CC * sizeof(float), stream);
    dim3 grid1(TT / TL, NN);              // 64 x 64 = 4096 blocks
    conv_store_stats<<<grid1, 256, 0, stream>>>(x, cw, buckets, out);
    norm_relu<<<NN * CC, 256, 0, stream>>>(buckets, gamma, beta, out);
}